// Round 9
// baseline (193.986 us; speedup 1.0000x reference)
//
#include <hip/hip_runtime.h>
#include <hip/hip_bf16.h>
#include <math.h>

// B=2, L=4, C=128, H=W=96. Only fusion target i=0 is consumed downstream.
// j=0 source is the identity warp: sel[b][0]==ego, roi[b][0]==1 (diag of P is I).
#define HW 9216
#define CC 128

typedef __attribute__((ext_vector_type(4))) float f32x4;
typedef __attribute__((ext_vector_type(8))) short s16x8;

static __device__ __forceinline__ unsigned short f2bf(float f) {
    __hip_bfloat16 h = __float2bfloat16(f);
    return *reinterpret_cast<unsigned short*>(&h);
}
static __device__ __forceinline__ float bf2f(unsigned short u) {
    unsigned int v = ((unsigned int)u) << 16;
    float f;
    __builtin_memcpy(&f, &v, 4);
    return f;
}

// ---------------- prep: theta (block 0) + bf16 weight tables ----------------
__global__ __launch_bounds__(256) void k_prep(const float* __restrict__ P,
                                              const float* __restrict__ w1, const float* __restrict__ w2,
                                              const float* __restrict__ mw,
                                              float* __restrict__ th,
                                              unsigned short* __restrict__ w1b, unsigned short* __restrict__ w2b,
                                              unsigned short* __restrict__ mwb) {
    int t = blockIdx.x * 256 + threadIdx.x;
    if (blockIdx.x == 0 && threadIdx.x < 8) {
        int i = threadIdx.x;
        const float* M = P + (size_t)i * 64;
        float a00 = M[0], a01 = M[1], a02 = M[3] / 1.6f;
        float a10 = M[4], a11 = M[5], a12 = M[7] / 1.6f;
        const float cx = 48.f, cy = 48.f;
        float T02 = cx - (a00 * cx + a01 * cy) + a02;
        float T12 = cy - (a10 * cx + a11 * cy) + a12;
        float A02 = a00 + a01 - 1.f + (2.f / 95.f) * T02;
        float A12 = a10 + a11 - 1.f + (2.f / 95.f) * T12;
        float det = a00 * a11 - a01 * a10;
        float i00 = a11 / det, i01 = -a01 / det, i10 = -a10 / det, i11 = a00 / det;
        float* o = th + i * 6;
        o[0] = i00; o[1] = i01; o[2] = -(i00 * A02 + i01 * A12);
        o[3] = i10; o[4] = i11; o[5] = -(i10 * A02 + i11 * A12);
    }
    int nthr = gridDim.x * 256;
    for (int i = t; i < 32768; i += nthr) w1b[i] = f2bf(w1[i]);
    for (int i = t; i < 16384; i += nthr) mwb[i] = f2bf(mw[i]);
    for (int i = t; i < 4096; i += nthr) w2b[i] = f2bf(w2[i]);
}

// ---------------- transpose x -> bf16 xT[bn][y][x][c]; fused agent-0 var sums ----------------
__global__ __launch_bounds__(256) void k_transpose(const float* __restrict__ x, unsigned short* __restrict__ xT,
                                                   float* __restrict__ vsum) {
    int bn = blockIdx.x / 96, y = blockIdx.x % 96;
    __shared__ float tile[96][129];
    const float* src = x + (size_t)bn * 128 * HW + (size_t)y * 96;
    for (int i = threadIdx.x; i < 128 * 96; i += 256) {
        int c = i / 96, xx = i - c * 96;
        tile[xx][c] = src[(size_t)c * HW + xx];
    }
    __syncthreads();
    unsigned int* dst = (unsigned int*)(xT + ((size_t)bn * 96 + y) * 96 * 128);
    for (int i = threadIdx.x; i < 96 * 64; i += 256) {
        int xx = i >> 6, cp = i & 63;
        unsigned int pk = (unsigned int)f2bf(tile[xx][cp * 2]) | ((unsigned int)f2bf(tile[xx][cp * 2 + 1]) << 16);
        dst[xx * 64 + cp] = pk;
    }
    if ((bn & 3) == 0 && threadIdx.x < 128) {
        int c = threadIdx.x;
        float s = 0.f, ss = 0.f;
        #pragma unroll 8
        for (int xx = 0; xx < 96; xx++) { float v = tile[xx][c]; s += v; ss += v * v; }
        float* vp = vsum + (size_t)((bn >> 2) * 128 + c) * 2;
        atomicAdd(vp, s);
        atomicAdd(vp + 1, ss);
    }
}

// ---------------- argmax of per-channel variance (ddof=1) ----------------
__global__ void k_argmax(const float* __restrict__ vsum, int* __restrict__ cmax) {
    int b = blockIdx.x, t = threadIdx.x;  // 128 threads
    __shared__ float v[128]; __shared__ int idx[128];
    float s = vsum[(b * 128 + t) * 2], ss = vsum[(b * 128 + t) * 2 + 1];
    float mean = s / 9216.f;
    v[t] = (ss - 9216.f * mean * mean) / 9215.f;
    idx[t] = t; __syncthreads();
    for (int o = 64; o > 0; o >>= 1) {
        if (t < o) { if (v[t + o] > v[t]) { v[t] = v[t + o]; idx[t] = idx[t + o]; } }
        __syncthreads();
    }
    if (t == 0) cmax[b] = idx[0];
}

// ---------------- gather (j=1..3): sel16[b3][p][c] bf16, roi[b3][p] ----------------
// 16 px/block, 16 threads per px each owning 8 channels (vectorized s16x8 corners).
__global__ __launch_bounds__(256) void k_gather(const unsigned short* __restrict__ xT, const float* __restrict__ th,
                                                const int* __restrict__ cmax, unsigned short* __restrict__ sel16,
                                                float* __restrict__ roi) {
    int blk = blockIdx.x;
    int bj6 = blk / 576, pblk = blk - bj6 * 576;
    int b = bj6 / 3, j = bj6 - b * 3 + 1;
    int pxr = threadIdx.x >> 4, g = threadIdx.x & 15;
    const float* t6 = th + (b * 4 + j) * 6;
    float T0 = t6[0], T1 = t6[1], T2 = t6[2], T3 = t6[3], T4 = t6[4], T5 = t6[5];
    int cm = cmax[b];
    const unsigned short* base = xT + (size_t)(b * 4 + j) * HW * CC;
    const unsigned short* ebase = xT + (size_t)(b * 4) * HW * CC;
    int p = pblk * 16 + pxr;
    int h = p / 96, w = p - h * 96;
    float X = -1.f + (2.f / 95.f) * (float)w, Y = -1.f + (2.f / 95.f) * (float)h;
    float gx = T0 * X + T1 * Y + T2;
    float gy = T3 * X + T4 * Y + T5;
    float px = (gx + 1.f) * 47.5f, py = (gy + 1.f) * 47.5f;
    float x0f = floorf(px), y0f = floorf(py);
    float wx = px - x0f, wy = py - y0f;
    int x0 = (int)x0f, y0 = (int)y0f, x1 = x0 + 1, y1 = y0 + 1;
    float w00 = (1.f - wx) * (1.f - wy), w10 = wx * (1.f - wy);
    float w01 = (1.f - wx) * wy, w11 = wx * wy;
    bool vx0 = (x0 >= 0) && (x0 <= 95), vx1 = (x1 >= 0) && (x1 <= 95);
    bool vy0 = (y0 >= 0) && (y0 <= 95), vy1 = (y1 >= 0) && (y1 <= 95);
    float f00 = (vx0 && vy0) ? w00 : 0.f, f10 = (vx1 && vy0) ? w10 : 0.f;
    float f01 = (vx0 && vy1) ? w01 : 0.f, f11 = (vx1 && vy1) ? w11 : 0.f;
    int xc0 = min(max(x0, 0), 95), xc1 = min(max(x1, 0), 95);
    int yc0 = min(max(y0, 0), 95), yc1 = min(max(y1, 0), 95);
    s16x8 v00 = *(const s16x8*)(base + (size_t)((95 - xc0) * 96 + yc0) * CC + g * 8);
    s16x8 v10 = *(const s16x8*)(base + (size_t)((95 - xc1) * 96 + yc0) * CC + g * 8);
    s16x8 v01 = *(const s16x8*)(base + (size_t)((95 - xc0) * 96 + yc1) * CC + g * 8);
    s16x8 v11 = *(const s16x8*)(base + (size_t)((95 - xc1) * 96 + yc1) * CC + g * 8);
    s16x8 ve  = *(const s16x8*)(ebase + (size_t)((95 - w) * 96 + h) * CC + g * 8);
    s16x8 sv;
    #pragma unroll
    for (int e = 0; e < 8; e++) {
        float nb = f00 * bf2f((unsigned short)v00[e]) + f10 * bf2f((unsigned short)v10[e])
                 + f01 * bf2f((unsigned short)v01[e]) + f11 * bf2f((unsigned short)v11[e]);
        int c = g * 8 + e;
        unsigned short r = (b == 0) ? f2bf(nb) : ((c == cm) ? f2bf(nb) : (unsigned short)ve[e]);
        sv[e] = (short)r;
    }
    *(s16x8*)(sel16 + ((size_t)bj6 * HW + p) * CC + g * 8) = sv;
    if (g == 0) roi[(size_t)bj6 * HW + p] = f00 + f10 + f01 + f11;
}

// ---------------- mega-fused, wave-per-source: MLP -> softmax -> combine -> final GEMM ----------------
// 256 thr (4 waves), 16 px/block, 1152 blocks. Wave w handles source j=w end-to-end.
// LDS ~34.6 KB -> 4 blocks/CU; __launch_bounds__(256,4) pins VGPR <= 128.
__global__ __launch_bounds__(256, 4) void k_fused(
    const unsigned short* __restrict__ xT, const unsigned short* __restrict__ sel16,
    const float* __restrict__ roiB,
    const unsigned short* __restrict__ w1b, const unsigned short* __restrict__ w2b,
    const unsigned short* __restrict__ mwb,
    const float* __restrict__ b1, const float* __restrict__ s1, const float* __restrict__ t1,
    const float* __restrict__ b2, const float* __restrict__ s2, const float* __restrict__ t2,
    const float* __restrict__ w3, const float* __restrict__ b3, const float* __restrict__ s3,
    const float* __restrict__ t3, const float* __restrict__ w4, const float* __restrict__ b4,
    const float* __restrict__ mb, float* __restrict__ out) {
    // layout: tiles j*4096 (j=0 ego, 16KB); wave scratch 16384 + w*4096 (l1T bf16 [16][256B],
    //         overlaid later by l2s f32 [16][36]); lgs @32768; rois @33024; w3s[8][36] @33280; cs3 @34432.
    __shared__ __align__(16) unsigned char sm[34560];
    float* lgs  = (float*)(sm + 32768);
    float* rois = (float*)(sm + 33024);
    float* w3s  = (float*)(sm + 33280);
    float* cs3  = (float*)(sm + 34432);
    int t = threadIdx.x;
    int blk = blockIdx.x;
    int b = blk / 576, pt = blk - b * 576;
    int p0 = pt * 16;
    // ---- stage: ego tile (slot 0) + 3 sel tiles, swizzled; 1 s16x8 per thread per tile ----
    const unsigned short* egb = xT + (size_t)(b * 4) * HW * CC;
    {
        int px = t >> 4, g = t & 15;
        int p = p0 + px;
        int h = p / 96, w = p - h * 96;
        s16x8 v = *(const s16x8*)(egb + (size_t)((95 - w) * 96 + h) * CC + g * 8);
        *(s16x8*)(sm + px * 256 + ((g * 16) ^ ((px & 7) << 4))) = v;
        #pragma unroll
        for (int j = 1; j < 4; j++) {
            const unsigned short* sp = sel16 + ((size_t)(b * 3 + j - 1) * HW + p0) * CC;
            s16x8 vj = *(const s16x8*)(sp + px * 128 + g * 8);
            *(s16x8*)(sm + j * 4096 + px * 256 + ((g * 16) ^ ((px & 7) << 4))) = vj;
        }
    }
    if (t < 64) {
        int j = t >> 4, px = t & 15;
        rois[j * 16 + px] = (j == 0) ? 1.f : roiB[(size_t)(b * 3 + j - 1) * HW + p0 + px];
    }
    { int o = t >> 5, k = t & 31; w3s[o * 36 + k] = w3[o * 32 + k]; }
    if (t < 8) { cs3[t] = b3[t]; cs3[8 + t] = s3[t]; cs3[16 + t] = t3[t]; cs3[24 + t] = w4[t]; }
    int lane = t & 63, w_ = t >> 6, l15 = lane & 15, l4 = lane >> 4;
    unsigned char* scratch = sm + 16384 + w_ * 4096;
    __syncthreads();   // barrier 1
    // ---- GEMM1 (source j=w_): C[16px][128] = [sel_j || ego][16][256] @ W1^T ----
    f32x4 acc[8];
    #pragma unroll
    for (int nt = 0; nt < 8; nt++) acc[nt] = f32x4{0.f, 0.f, 0.f, 0.f};
    const unsigned char* tj = sm + w_ * 4096;
    #pragma unroll
    for (int kt = 0; kt < 8; kt++) {
        const unsigned char* asrc = (kt < 4) ? tj : sm;   // cols 128..255 = ego tile
        int kb = (kt & 3) * 64 + l4 * 16;
        s16x8 af = *(const s16x8*)(asrc + l15 * 256 + (kb ^ ((l15 & 7) << 4)));
        #pragma unroll
        for (int nt = 0; nt < 8; nt++) {
            s16x8 bf = *(const s16x8*)(w1b + (size_t)(nt * 16 + l15) * 256 + kt * 32 + l4 * 8);
            acc[nt] = __builtin_amdgcn_mfma_f32_16x16x32_bf16(af, bf, acc[nt], 0, 0, 0);
        }
    }
    // ---- epilogue1: affine+relu -> wave-private l1T bf16 [16][128] swizzled ----
    #pragma unroll
    for (int nt = 0; nt < 8; nt++) {
        int o = nt * 16 + l15;
        float bb = b1[o], sv = s1[o], tv = t1[o];
        #pragma unroll
        for (int r = 0; r < 4; r++) {
            int px = l4 * 4 + r;
            float v = fmaxf((acc[nt][r] + bb) * sv + tv, 0.f);
            *(unsigned short*)(scratch + px * 256 + ((2 * o) ^ ((px & 7) << 4))) = f2bf(v);
        }
    }
    asm volatile("s_waitcnt lgkmcnt(0)" ::: "memory");
    // ---- GEMM2: C[16px][32] = L1[16][128] @ W2^T (whole wave) ----
    f32x4 acc2[2];
    acc2[0] = f32x4{0.f, 0.f, 0.f, 0.f};
    acc2[1] = f32x4{0.f, 0.f, 0.f, 0.f};
    #pragma unroll
    for (int kt = 0; kt < 4; kt++) {
        s16x8 af2 = *(const s16x8*)(scratch + l15 * 256 + ((2 * (kt * 32 + l4 * 8)) ^ ((l15 & 7) << 4)));
        #pragma unroll
        for (int nt = 0; nt < 2; nt++) {
            s16x8 bf = *(const s16x8*)(w2b + (size_t)(nt * 16 + l15) * 128 + kt * 32 + l4 * 8);
            acc2[nt] = __builtin_amdgcn_mfma_f32_16x16x32_bf16(af2, bf, acc2[nt], 0, 0, 0);
        }
    }
    asm volatile("s_waitcnt lgkmcnt(0)" ::: "memory");
    // ---- epilogue2: affine+relu -> l2s f32 [16][36] (overlays scratch; same wave only) ----
    float* l2s = (float*)scratch;
    #pragma unroll
    for (int nt = 0; nt < 2; nt++) {
        int o = nt * 16 + l15;
        float bb = b2[o], sv = s2[o], tv = t2[o];
        #pragma unroll
        for (int r = 0; r < 4; r++) {
            int px = l4 * 4 + r;
            l2s[px * 36 + o] = fmaxf((acc2[nt][r] + bb) * sv + tv, 0.f);
        }
    }
    asm volatile("s_waitcnt lgkmcnt(0)" ::: "memory");
    // ---- layers 3+4 fp32 (lanes 0..15 of EVERY wave, concurrent across sources) ----
    if (lane < 16) {
        int px = lane;
        f32x4 xv[8];
        #pragma unroll
        for (int kc = 0; kc < 8; kc++) xv[kc] = *(const f32x4*)(l2s + px * 36 + kc * 4);
        float lg = b4[0];
        #pragma unroll
        for (int o = 0; o < 8; o++) {
            float a = 0.f;
            #pragma unroll
            for (int kc = 0; kc < 8; kc++) {
                f32x4 wv = *(const f32x4*)(w3s + o * 36 + kc * 4);
                a += xv[kc][0] * wv[0] + xv[kc][1] * wv[1] + xv[kc][2] * wv[2] + xv[kc][3] * wv[3];
            }
            float l3 = fmaxf((a + cs3[o]) * cs3[8 + o] + cs3[16 + o], 0.f);
            lg += cs3[24 + o] * l3;
        }
        lgs[w_ * 16 + px] = fmaxf(lg, 0.f);
    }
    __syncthreads();   // barrier 2
    // ---- softmax weights (per lane, for its A-frag row px = l15) ----
    float wgt[4];
    {
        int px = l15;
        float rr[4], lg[4];
        #pragma unroll
        for (int j = 0; j < 4; j++) { rr[j] = rois[j * 16 + px]; lg[j] = lgs[j * 16 + px]; }
        float m = -1e30f;
        #pragma unroll
        for (int j = 0; j < 4; j++) if (rr[j] != 0.f && lg[j] > m) m = lg[j];
        float e[4], se = 0.f;
        #pragma unroll
        for (int j = 0; j < 4; j++) { e[j] = (rr[j] != 0.f) ? expf(lg[j] - m) : 0.f; se += e[j]; }
        float inv = 1.f / se;
        #pragma unroll
        for (int j = 0; j < 4; j++) wgt[j] = e[j] * inv * rr[j];
    }
    // ---- combine (in-register, from LDS tiles) + final GEMM; wave owns out cols w_*32..+31 ----
    f32x4 acc3[2];
    acc3[0] = f32x4{0.f, 0.f, 0.f, 0.f};
    acc3[1] = f32x4{0.f, 0.f, 0.f, 0.f};
    #pragma unroll
    for (int kt = 0; kt < 4; kt++) {
        int byo = (kt * 64 + l4 * 16) ^ ((l15 & 7) << 4);
        float accv[8];
        #pragma unroll
        for (int e = 0; e < 8; e++) accv[e] = 0.f;
        #pragma unroll
        for (int j = 0; j < 4; j++) {
            s16x8 v = *(const s16x8*)(sm + j * 4096 + l15 * 256 + byo);
            float wj = wgt[j];
            #pragma unroll
            for (int e = 0; e < 8; e++) accv[e] += wj * bf2f((unsigned short)v[e]);
        }
        s16x8 af;
        #pragma unroll
        for (int e = 0; e < 8; e++) af[e] = (short)f2bf(accv[e]);
        #pragma unroll
        for (int nt = 0; nt < 2; nt++) {
            s16x8 bfr = *(const s16x8*)(mwb + (size_t)(w_ * 32 + nt * 16 + l15) * 128 + kt * 32 + l4 * 8);
            acc3[nt] = __builtin_amdgcn_mfma_f32_16x16x32_bf16(af, bfr, acc3[nt], 0, 0, 0);
        }
    }
    float mbv[2];
    #pragma unroll
    for (int nt = 0; nt < 2; nt++) mbv[nt] = mb[w_ * 32 + nt * 16 + l15];
    #pragma unroll
    for (int nt = 0; nt < 2; nt++) {
        #pragma unroll
        for (int r = 0; r < 4; r++) {
            int px = l4 * 4 + r;
            int p = p0 + px;
            int h = p / 96, ww = p - h * 96;
            out[(((size_t)b * 96 + (95 - ww)) * 96 + h) * CC + w_ * 32 + nt * 16 + l15] = acc3[nt][r] + mbv[nt];
        }
    }
}

extern "C" void kernel_launch(void* const* d_in, const int* in_sizes, int n_in,
                              void* d_out, int out_size, void* d_ws, size_t ws_size,
                              hipStream_t stream) {
    const float* x  = (const float*)d_in[0];
    const float* P  = (const float*)d_in[2];
    const float* w1 = (const float*)d_in[3];
    const float* b1 = (const float*)d_in[4];
    const float* s1 = (const float*)d_in[5];
    const float* t1 = (const float*)d_in[6];
    const float* w2 = (const float*)d_in[7];
    const float* b2 = (const float*)d_in[8];
    const float* s2 = (const float*)d_in[9];
    const float* t2 = (const float*)d_in[10];
    const float* w3 = (const float*)d_in[11];
    const float* b3 = (const float*)d_in[12];
    const float* s3 = (const float*)d_in[13];
    const float* t3 = (const float*)d_in[14];
    const float* w4 = (const float*)d_in[15];
    const float* b4 = (const float*)d_in[16];
    const float* mw = (const float*)d_in[17];
    const float* mb = (const float*)d_in[18];
    float* out = (float*)d_out;

    float* ws = (float*)d_ws;
    float* TH   = ws;                                     // 48 (pad 64)
    float* VSUM = ws + 64;                                // [2][128][2] = 512
    int*   CMX  = (int*)(ws + 576);                       // 2 (pad to 1024)
    unsigned short* XT    = (unsigned short*)(ws + 1024); // 8*HW*128 = 9437184 bf16
    unsigned short* SEL16 = XT + 9437184;                 // 6*HW*128 = 7077888 bf16
    float* ROI = (float*)(SEL16 + 7077888);               // 6*HW = 55296
    unsigned short* W1B = (unsigned short*)(ROI + 55296); // 32768
    unsigned short* W2B = W1B + 32768;                    // 4096
    unsigned short* MWB = W2B + 4096;                     // 16384

    hipMemsetAsync(VSUM, 0, 512 * sizeof(float), stream);
    k_prep<<<16, 256, 0, stream>>>(P, w1, w2, mw, TH, W1B, W2B, MWB);
    k_transpose<<<768, 256, 0, stream>>>(x, XT, VSUM);
    k_argmax<<<2, 128, 0, stream>>>(VSUM, CMX);
    k_gather<<<3456, 256, 0, stream>>>(XT, TH, CMX, SEL16, ROI);
    k_fused<<<1152, 256, 0, stream>>>(XT, SEL16, ROI, W1B, W2B, MWB,
                                      b1, s1, t1, b2, s2, t2, w3, b3, s3, t3, w4, b4, mb, out);
}

// Round 11
// 165.582 us; speedup vs baseline: 1.1715x; 1.1715x over previous
//
#include <hip/hip_runtime.h>
#include <hip/hip_bf16.h>
#include <math.h>

// B=2, L=4, C=128, H=W=96. Only fusion target i=0 is consumed downstream.
// j=0 source is the identity warp: sel[b][0]==ego, roi[b][0]==1 (diag of P is I).
#define HW 9216
#define CC 128

typedef __attribute__((ext_vector_type(4))) float f32x4;
typedef __attribute__((ext_vector_type(8))) short s16x8;

static __device__ __forceinline__ unsigned short f2bf(float f) {
    __hip_bfloat16 h = __float2bfloat16(f);
    return *reinterpret_cast<unsigned short*>(&h);
}
static __device__ __forceinline__ float bf2f(unsigned short u) {
    unsigned int v = ((unsigned int)u) << 16;
    float f;
    __builtin_memcpy(&f, &v, 4);
    return f;
}

// ---------------- prep: theta (block 0) + FRAGMENT-PACKED bf16 weight tables ----------------
// B-frag for mfma_16x16x32: lane reads w[(nt*16+(lane&15))*K + kt*32 + (lane>>4)*8 + e].
// We pre-permute so the wave's 64 lanes read one contiguous 1KB chunk per (kt,nt) slot.
__global__ __launch_bounds__(256) void k_prep(const float* __restrict__ P,
                                              const float* __restrict__ w1, const float* __restrict__ w2,
                                              const float* __restrict__ mw,
                                              float* __restrict__ th,
                                              unsigned short* __restrict__ w1b, unsigned short* __restrict__ w2b,
                                              unsigned short* __restrict__ mwb) {
    int t = blockIdx.x * 256 + threadIdx.x;
    if (blockIdx.x == 0 && threadIdx.x < 8) {
        int i = threadIdx.x;
        const float* M = P + (size_t)i * 64;
        float a00 = M[0], a01 = M[1], a02 = M[3] / 1.6f;
        float a10 = M[4], a11 = M[5], a12 = M[7] / 1.6f;
        const float cx = 48.f, cy = 48.f;
        float T02 = cx - (a00 * cx + a01 * cy) + a02;
        float T12 = cy - (a10 * cx + a11 * cy) + a12;
        float A02 = a00 + a01 - 1.f + (2.f / 95.f) * T02;
        float A12 = a10 + a11 - 1.f + (2.f / 95.f) * T12;
        float det = a00 * a11 - a01 * a10;
        float i00 = a11 / det, i01 = -a01 / det, i10 = -a10 / det, i11 = a00 / det;
        float* o = th + i * 6;
        o[0] = i00; o[1] = i01; o[2] = -(i00 * A02 + i01 * A12);
        o[3] = i10; o[4] = i11; o[5] = -(i10 * A02 + i11 * A12);
    }
    int nthr = gridDim.x * 256;
    // w1 [128][256] -> slots (kt*8+nt), kt<8, nt<8
    for (int i = t; i < 32768; i += nthr) {
        int e = i & 7, lane = (i >> 3) & 63, slot = i >> 9;
        int nt = slot & 7, kt = slot >> 3;
        int row = nt * 16 + (lane & 15), col = kt * 32 + (lane >> 4) * 8 + e;
        w1b[i] = f2bf(w1[row * 256 + col]);
    }
    // mw [128][128] -> slots (wq*8 + kt*2 + nt), wq<4, kt<4, nt<2
    for (int i = t; i < 16384; i += nthr) {
        int e = i & 7, lane = (i >> 3) & 63, slot = i >> 9;
        int nt = slot & 1, kt = (slot >> 1) & 3, wq = slot >> 3;
        int row = wq * 32 + nt * 16 + (lane & 15), col = kt * 32 + (lane >> 4) * 8 + e;
        mwb[i] = f2bf(mw[row * 128 + col]);
    }
    // w2 [32][128] -> slots (kt*2+nt), kt<4, nt<2
    for (int i = t; i < 4096; i += nthr) {
        int e = i & 7, lane = (i >> 3) & 63, slot = i >> 9;
        int nt = slot & 1, kt = slot >> 1;
        int row = nt * 16 + (lane & 15), col = kt * 32 + (lane >> 4) * 8 + e;
        w2b[i] = f2bf(w2[row * 128 + col]);
    }
}

// ---------------- transpose x -> bf16 xT[bn][y][x][c]; fused agent-0 var sums ----------------
__global__ __launch_bounds__(256) void k_transpose(const float* __restrict__ x, unsigned short* __restrict__ xT,
                                                   float* __restrict__ vsum) {
    int bn = blockIdx.x / 96, y = blockIdx.x % 96;
    __shared__ float tile[96][129];
    const float* src = x + (size_t)bn * 128 * HW + (size_t)y * 96;
    for (int i = threadIdx.x; i < 128 * 96; i += 256) {
        int c = i / 96, xx = i - c * 96;
        tile[xx][c] = src[(size_t)c * HW + xx];
    }
    __syncthreads();
    unsigned int* dst = (unsigned int*)(xT + ((size_t)bn * 96 + y) * 96 * 128);
    for (int i = threadIdx.x; i < 96 * 64; i += 256) {
        int xx = i >> 6, cp = i & 63;
        unsigned int pk = (unsigned int)f2bf(tile[xx][cp * 2]) | ((unsigned int)f2bf(tile[xx][cp * 2 + 1]) << 16);
        dst[xx * 64 + cp] = pk;
    }
    if ((bn & 3) == 0 && threadIdx.x < 128) {
        int c = threadIdx.x;
        float s = 0.f, ss = 0.f;
        #pragma unroll 8
        for (int xx = 0; xx < 96; xx++) { float v = tile[xx][c]; s += v; ss += v * v; }
        float* vp = vsum + (size_t)((bn >> 2) * 128 + c) * 2;
        atomicAdd(vp, s);
        atomicAdd(vp + 1, ss);
    }
}

// ---------------- argmax of per-channel variance (ddof=1) ----------------
__global__ void k_argmax(const float* __restrict__ vsum, int* __restrict__ cmax) {
    int b = blockIdx.x, t = threadIdx.x;  // 128 threads
    __shared__ float v[128]; __shared__ int idx[128];
    float s = vsum[(b * 128 + t) * 2], ss = vsum[(b * 128 + t) * 2 + 1];
    float mean = s / 9216.f;
    v[t] = (ss - 9216.f * mean * mean) / 9215.f;
    idx[t] = t; __syncthreads();
    for (int o = 64; o > 0; o >>= 1) {
        if (t < o) { if (v[t + o] > v[t]) { v[t] = v[t + o]; idx[t] = idx[t + o]; } }
        __syncthreads();
    }
    if (t == 0) cmax[b] = idx[0];
}

// ---------------- gather (j=1..3): sel16[b3][p][c] bf16, roi[b3][p] ----------------
__global__ __launch_bounds__(256) void k_gather(const unsigned short* __restrict__ xT, const float* __restrict__ th,
                                                const int* __restrict__ cmax, unsigned short* __restrict__ sel16,
                                                float* __restrict__ roi) {
    int blk = blockIdx.x;
    int bj6 = blk / 576, pblk = blk - bj6 * 576;
    int b = bj6 / 3, j = bj6 - b * 3 + 1;
    int pxr = threadIdx.x >> 4, g = threadIdx.x & 15;
    const float* t6 = th + (b * 4 + j) * 6;
    float T0 = t6[0], T1 = t6[1], T2 = t6[2], T3 = t6[3], T4 = t6[4], T5 = t6[5];
    int cm = cmax[b];
    const unsigned short* base = xT + (size_t)(b * 4 + j) * HW * CC;
    const unsigned short* ebase = xT + (size_t)(b * 4) * HW * CC;
    int p = pblk * 16 + pxr;
    int h = p / 96, w = p - h * 96;
    float X = -1.f + (2.f / 95.f) * (float)w, Y = -1.f + (2.f / 95.f) * (float)h;
    float gx = T0 * X + T1 * Y + T2;
    float gy = T3 * X + T4 * Y + T5;
    float px = (gx + 1.f) * 47.5f, py = (gy + 1.f) * 47.5f;
    float x0f = floorf(px), y0f = floorf(py);
    float wx = px - x0f, wy = py - y0f;
    int x0 = (int)x0f, y0 = (int)y0f, x1 = x0 + 1, y1 = y0 + 1;
    float w00 = (1.f - wx) * (1.f - wy), w10 = wx * (1.f - wy);
    float w01 = (1.f - wx) * wy, w11 = wx * wy;
    bool vx0 = (x0 >= 0) && (x0 <= 95), vx1 = (x1 >= 0) && (x1 <= 95);
    bool vy0 = (y0 >= 0) && (y0 <= 95), vy1 = (y1 >= 0) && (y1 <= 95);
    float f00 = (vx0 && vy0) ? w00 : 0.f, f10 = (vx1 && vy0) ? w10 : 0.f;
    float f01 = (vx0 && vy1) ? w01 : 0.f, f11 = (vx1 && vy1) ? w11 : 0.f;
    int xc0 = min(max(x0, 0), 95), xc1 = min(max(x1, 0), 95);
    int yc0 = min(max(y0, 0), 95), yc1 = min(max(y1, 0), 95);
    s16x8 v00 = *(const s16x8*)(base + (size_t)((95 - xc0) * 96 + yc0) * CC + g * 8);
    s16x8 v10 = *(const s16x8*)(base + (size_t)((95 - xc1) * 96 + yc0) * CC + g * 8);
    s16x8 v01 = *(const s16x8*)(base + (size_t)((95 - xc0) * 96 + yc1) * CC + g * 8);
    s16x8 v11 = *(const s16x8*)(base + (size_t)((95 - xc1) * 96 + yc1) * CC + g * 8);
    s16x8 ve  = *(const s16x8*)(ebase + (size_t)((95 - w) * 96 + h) * CC + g * 8);
    s16x8 sv;
    #pragma unroll
    for (int e = 0; e < 8; e++) {
        float nb = f00 * bf2f((unsigned short)v00[e]) + f10 * bf2f((unsigned short)v10[e])
                 + f01 * bf2f((unsigned short)v01[e]) + f11 * bf2f((unsigned short)v11[e]);
        int c = g * 8 + e;
        unsigned short r = (b == 0) ? f2bf(nb) : ((c == cm) ? f2bf(nb) : (unsigned short)ve[e]);
        sv[e] = (short)r;
    }
    *(s16x8*)(sel16 + ((size_t)bj6 * HW + p) * CC + g * 8) = sv;
    if (g == 0) roi[(size_t)bj6 * HW + p] = f00 + f10 + f01 + f11;
}

// ---------------- mega-fused, wave-per-source: MLP -> softmax -> combine -> final GEMM ----------------
// 256 thr (4 waves), 16 px/block, 1152 blocks. Identical geometry to round 9;
// ONLY change: B-frag weight loads are now contiguous (fragment-packed tables).
__global__ __launch_bounds__(256, 4) void k_fused(
    const unsigned short* __restrict__ xT, const unsigned short* __restrict__ sel16,
    const float* __restrict__ roiB,
    const unsigned short* __restrict__ w1b, const unsigned short* __restrict__ w2b,
    const unsigned short* __restrict__ mwb,
    const float* __restrict__ b1, const float* __restrict__ s1, const float* __restrict__ t1,
    const float* __restrict__ b2, const float* __restrict__ s2, const float* __restrict__ t2,
    const float* __restrict__ w3, const float* __restrict__ b3, const float* __restrict__ s3,
    const float* __restrict__ t3, const float* __restrict__ w4, const float* __restrict__ b4,
    const float* __restrict__ mb, float* __restrict__ out) {
    __shared__ __align__(16) unsigned char sm[34560];
    float* lgs  = (float*)(sm + 32768);
    float* rois = (float*)(sm + 33024);
    float* w3s  = (float*)(sm + 33280);
    float* cs3  = (float*)(sm + 34432);
    int t = threadIdx.x;
    int blk = blockIdx.x;
    int b = blk / 576, pt = blk - b * 576;
    int p0 = pt * 16;
    const unsigned short* egb = xT + (size_t)(b * 4) * HW * CC;
    {
        int px = t >> 4, g = t & 15;
        int p = p0 + px;
        int h = p / 96, w = p - h * 96;
        s16x8 v = *(const s16x8*)(egb + (size_t)((95 - w) * 96 + h) * CC + g * 8);
        *(s16x8*)(sm + px * 256 + ((g * 16) ^ ((px & 7) << 4))) = v;
        #pragma unroll
        for (int j = 1; j < 4; j++) {
            const unsigned short* sp = sel16 + ((size_t)(b * 3 + j - 1) * HW + p0) * CC;
            s16x8 vj = *(const s16x8*)(sp + px * 128 + g * 8);
            *(s16x8*)(sm + j * 4096 + px * 256 + ((g * 16) ^ ((px & 7) << 4))) = vj;
        }
    }
    if (t < 64) {
        int j = t >> 4, px = t & 15;
        rois[j * 16 + px] = (j == 0) ? 1.f : roiB[(size_t)(b * 3 + j - 1) * HW + p0 + px];
    }
    { int o = t >> 5, k = t & 31; w3s[o * 36 + k] = w3[o * 32 + k]; }
    if (t < 8) { cs3[t] = b3[t]; cs3[8 + t] = s3[t]; cs3[16 + t] = t3[t]; cs3[24 + t] = w4[t]; }
    int lane = t & 63, w_ = t >> 6, l15 = lane & 15, l4 = lane >> 4;
    unsigned char* scratch = sm + 16384 + w_ * 4096;
    __syncthreads();   // barrier 1
    // ---- GEMM1 (source j=w_): C[16px][128] = [sel_j || ego][16][256] @ W1^T ----
    f32x4 acc[8];
    #pragma unroll
    for (int nt = 0; nt < 8; nt++) acc[nt] = f32x4{0.f, 0.f, 0.f, 0.f};
    const unsigned char* tj = sm + w_ * 4096;
    #pragma unroll
    for (int kt = 0; kt < 8; kt++) {
        const unsigned char* asrc = (kt < 4) ? tj : sm;   // cols 128..255 = ego tile
        int kb = (kt & 3) * 64 + l4 * 16;
        s16x8 af = *(const s16x8*)(asrc + l15 * 256 + (kb ^ ((l15 & 7) << 4)));
        #pragma unroll
        for (int nt = 0; nt < 8; nt++) {
            s16x8 bf = *(const s16x8*)(w1b + (size_t)((kt * 8 + nt) * 64 + lane) * 8);
            acc[nt] = __builtin_amdgcn_mfma_f32_16x16x32_bf16(af, bf, acc[nt], 0, 0, 0);
        }
    }
    // ---- epilogue1: affine+relu -> wave-private l1T bf16 [16][128] swizzled ----
    #pragma unroll
    for (int nt = 0; nt < 8; nt++) {
        int o = nt * 16 + l15;
        float bb = b1[o], sv = s1[o], tv = t1[o];
        #pragma unroll
        for (int r = 0; r < 4; r++) {
            int px = l4 * 4 + r;
            float v = fmaxf((acc[nt][r] + bb) * sv + tv, 0.f);
            *(unsigned short*)(scratch + px * 256 + ((2 * o) ^ ((px & 7) << 4))) = f2bf(v);
        }
    }
    asm volatile("s_waitcnt lgkmcnt(0)" ::: "memory");
    // ---- GEMM2: C[16px][32] = L1[16][128] @ W2^T (whole wave) ----
    f32x4 acc2[2];
    acc2[0] = f32x4{0.f, 0.f, 0.f, 0.f};
    acc2[1] = f32x4{0.f, 0.f, 0.f, 0.f};
    #pragma unroll
    for (int kt = 0; kt < 4; kt++) {
        s16x8 af2 = *(const s16x8*)(scratch + l15 * 256 + ((2 * (kt * 32 + l4 * 8)) ^ ((l15 & 7) << 4)));
        #pragma unroll
        for (int nt = 0; nt < 2; nt++) {
            s16x8 bf = *(const s16x8*)(w2b + (size_t)((kt * 2 + nt) * 64 + lane) * 8);
            acc2[nt] = __builtin_amdgcn_mfma_f32_16x16x32_bf16(af2, bf, acc2[nt], 0, 0, 0);
        }
    }
    asm volatile("s_waitcnt lgkmcnt(0)" ::: "memory");
    // ---- epilogue2: affine+relu -> l2s f32 [16][36] (overlays scratch; same wave only) ----
    float* l2s = (float*)scratch;
    #pragma unroll
    for (int nt = 0; nt < 2; nt++) {
        int o = nt * 16 + l15;
        float bb = b2[o], sv = s2[o], tv = t2[o];
        #pragma unroll
        for (int r = 0; r < 4; r++) {
            int px = l4 * 4 + r;
            l2s[px * 36 + o] = fmaxf((acc2[nt][r] + bb) * sv + tv, 0.f);
        }
    }
    asm volatile("s_waitcnt lgkmcnt(0)" ::: "memory");
    // ---- layers 3+4 fp32 (lanes 0..15 of EVERY wave, concurrent across sources) ----
    if (lane < 16) {
        int px = lane;
        f32x4 xv[8];
        #pragma unroll
        for (int kc = 0; kc < 8; kc++) xv[kc] = *(const f32x4*)(l2s + px * 36 + kc * 4);
        float lg = b4[0];
        #pragma unroll
        for (int o = 0; o < 8; o++) {
            float a = 0.f;
            #pragma unroll
            for (int kc = 0; kc < 8; kc++) {
                f32x4 wv = *(const f32x4*)(w3s + o * 36 + kc * 4);
                a += xv[kc][0] * wv[0] + xv[kc][1] * wv[1] + xv[kc][2] * wv[2] + xv[kc][3] * wv[3];
            }
            float l3 = fmaxf((a + cs3[o]) * cs3[8 + o] + cs3[16 + o], 0.f);
            lg += cs3[24 + o] * l3;
        }
        lgs[w_ * 16 + px] = fmaxf(lg, 0.f);
    }
    __syncthreads();   // barrier 2
    // ---- softmax weights (per lane, for its A-frag row px = l15) ----
    float wgt[4];
    {
        int px = l15;
        float rr[4], lg[4];
        #pragma unroll
        for (int j = 0; j < 4; j++) { rr[j] = rois[j * 16 + px]; lg[j] = lgs[j * 16 + px]; }
        float m = -1e30f;
        #pragma unroll
        for (int j = 0; j < 4; j++) if (rr[j] != 0.f && lg[j] > m) m = lg[j];
        float e[4], se = 0.f;
        #pragma unroll
        for (int j = 0; j < 4; j++) { e[j] = (rr[j] != 0.f) ? expf(lg[j] - m) : 0.f; se += e[j]; }
        float inv = 1.f / se;
        #pragma unroll
        for (int j = 0; j < 4; j++) wgt[j] = e[j] * inv * rr[j];
    }
    // ---- combine (in-register, from LDS tiles) + final GEMM; wave owns out cols w_*32..+31 ----
    f32x4 acc3[2];
    acc3[0] = f32x4{0.f, 0.f, 0.f, 0.f};
    acc3[1] = f32x4{0.f, 0.f, 0.f, 0.f};
    #pragma unroll
    for (int kt = 0; kt < 4; kt++) {
        int byo = (kt * 64 + l4 * 16) ^ ((l15 & 7) << 4);
        float accv[8];
        #pragma unroll
        for (int e = 0; e < 8; e++) accv[e] = 0.f;
        #pragma unroll
        for (int j = 0; j < 4; j++) {
            s16x8 v = *(const s16x8*)(sm + j * 4096 + l15 * 256 + byo);
            float wj = wgt[j];
            #pragma unroll
            for (int e = 0; e < 8; e++) accv[e] += wj * bf2f((unsigned short)v[e]);
        }
        s16x8 af;
        #pragma unroll
        for (int e = 0; e < 8; e++) af[e] = (short)f2bf(accv[e]);
        #pragma unroll
        for (int nt = 0; nt < 2; nt++) {
            s16x8 bfr = *(const s16x8*)(mwb + (size_t)((w_ * 8 + kt * 2 + nt) * 64 + lane) * 8);
            acc3[nt] = __builtin_amdgcn_mfma_f32_16x16x32_bf16(af, bfr, acc3[nt], 0, 0, 0);
        }
    }
    float mbv[2];
    #pragma unroll
    for (int nt = 0; nt < 2; nt++) mbv[nt] = mb[w_ * 32 + nt * 16 + l15];
    #pragma unroll
    for (int nt = 0; nt < 2; nt++) {
        #pragma unroll
        for (int r = 0; r < 4; r++) {
            int px = l4 * 4 + r;
            int p = p0 + px;
            int h = p / 96, ww = p - h * 96;
            out[(((size_t)b * 96 + (95 - ww)) * 96 + h) * CC + w_ * 32 + nt * 16 + l15] = acc3[nt][r] + mbv[nt];
        }
    }
}

extern "C" void kernel_launch(void* const* d_in, const int* in_sizes, int n_in,
                              void* d_out, int out_size, void* d_ws, size_t ws_size,
                              hipStream_t stream) {
    const float* x  = (const float*)d_in[0];
    const float* P  = (const float*)d_in[2];
    const float* w1 = (const float*)d_in[3];
    const float* b1 = (const float*)d_in[4];
    const float* s1 = (const float*)d_in[5];
    const float* t1 = (const float*)d_in[6];
    const float* w2 = (const float*)d_in[7];
    const float* b2 = (const float*)d_in[8];
    const float* s2 = (const float*)d_in[9];
    const float* t2 = (const float*)d_in[10];
    const float* w3 = (const float*)d_in[11];
    const float* b3 = (const float*)d_in[12];
    const float* s3 = (const float*)d_in[13];
    const float* t3 = (const float*)d_in[14];
    const float* w4 = (const float*)d_in[15];
    const float* b4 = (const float*)d_in[16];
    const float* mw = (const float*)d_in[17];
    const float* mb = (const float*)d_in[18];
    float* out = (float*)d_out;

    float* ws = (float*)d_ws;
    float* TH   = ws;                                     // 48 (pad 64)
    float* VSUM = ws + 64;                                // [2][128][2] = 512
    int*   CMX  = (int*)(ws + 576);                       // 2 (pad to 1024)
    unsigned short* XT    = (unsigned short*)(ws + 1024); // 8*HW*128 = 9437184 bf16
    unsigned short* SEL16 = XT + 9437184;                 // 6*HW*128 = 7077888 bf16
    float* ROI = (float*)(SEL16 + 7077888);               // 6*HW = 55296
    unsigned short* W1B = (unsigned short*)(ROI + 55296); // 32768
    unsigned short* W2B = W1B + 32768;                    // 4096
    unsigned short* MWB = W2B + 4096;                     // 16384

    hipMemsetAsync(VSUM, 0, 512 * sizeof(float), stream);
    k_prep<<<16, 256, 0, stream>>>(P, w1, w2, mw, TH, W1B, W2B, MWB);
    k_transpose<<<768, 256, 0, stream>>>(x, XT, VSUM);
    k_argmax<<<2, 128, 0, stream>>>(VSUM, CMX);
    k_gather<<<3456, 256, 0, stream>>>(XT, TH, CMX, SEL16, ROI);
    k_fused<<<1152, 256, 0, stream>>>(XT, SEL16, ROI, W1B, W2B, MWB,
                                      b1, s1, t1, b2, s2, t2, w3, b3, s3, t3, w4, b4, mb, out);
}

// Round 12
// 157.980 us; speedup vs baseline: 1.2279x; 1.0481x over previous
//
#include <hip/hip_runtime.h>
#include <hip/hip_bf16.h>
#include <math.h>

// B=2, L=4, C=128, H=W=96. Only fusion target i=0 is consumed downstream.
// j=0 source is the identity warp: sel[b][0]==ego, roi[b][0]==1 (diag of P is I).
#define HW 9216
#define CC 128

typedef __attribute__((ext_vector_type(4))) float f32x4;
typedef __attribute__((ext_vector_type(8))) short s16x8;

static __device__ __forceinline__ unsigned short f2bf(float f) {
    __hip_bfloat16 h = __float2bfloat16(f);
    return *reinterpret_cast<unsigned short*>(&h);
}
static __device__ __forceinline__ float bf2f(unsigned short u) {
    unsigned int v = ((unsigned int)u) << 16;
    float f;
    __builtin_memcpy(&f, &v, 4);
    return f;
}

// ---------------- prep: theta (block 0) + FRAGMENT-PACKED bf16 weight tables ----------------
__global__ __launch_bounds__(256) void k_prep(const float* __restrict__ P,
                                              const float* __restrict__ w1, const float* __restrict__ w2,
                                              const float* __restrict__ mw,
                                              float* __restrict__ th,
                                              unsigned short* __restrict__ w1b, unsigned short* __restrict__ w2b,
                                              unsigned short* __restrict__ mwb) {
    int t = blockIdx.x * 256 + threadIdx.x;
    if (blockIdx.x == 0 && threadIdx.x < 8) {
        int i = threadIdx.x;
        const float* M = P + (size_t)i * 64;
        float a00 = M[0], a01 = M[1], a02 = M[3] / 1.6f;
        float a10 = M[4], a11 = M[5], a12 = M[7] / 1.6f;
        const float cx = 48.f, cy = 48.f;
        float T02 = cx - (a00 * cx + a01 * cy) + a02;
        float T12 = cy - (a10 * cx + a11 * cy) + a12;
        float A02 = a00 + a01 - 1.f + (2.f / 95.f) * T02;
        float A12 = a10 + a11 - 1.f + (2.f / 95.f) * T12;
        float det = a00 * a11 - a01 * a10;
        float i00 = a11 / det, i01 = -a01 / det, i10 = -a10 / det, i11 = a00 / det;
        float* o = th + i * 6;
        o[0] = i00; o[1] = i01; o[2] = -(i00 * A02 + i01 * A12);
        o[3] = i10; o[4] = i11; o[5] = -(i10 * A02 + i11 * A12);
    }
    int nthr = gridDim.x * 256;
    // w1 [128][256] -> slots (kt*8+nt), kt<8, nt<8
    for (int i = t; i < 32768; i += nthr) {
        int e = i & 7, lane = (i >> 3) & 63, slot = i >> 9;
        int nt = slot & 7, kt = slot >> 3;
        int row = nt * 16 + (lane & 15), col = kt * 32 + (lane >> 4) * 8 + e;
        w1b[i] = f2bf(w1[row * 256 + col]);
    }
    // mw [128][128] -> slots (wq*8 + kt*2 + nt), wq<4, kt<4, nt<2
    for (int i = t; i < 16384; i += nthr) {
        int e = i & 7, lane = (i >> 3) & 63, slot = i >> 9;
        int nt = slot & 1, kt = (slot >> 1) & 3, wq = slot >> 3;
        int row = wq * 32 + nt * 16 + (lane & 15), col = kt * 32 + (lane >> 4) * 8 + e;
        mwb[i] = f2bf(mw[row * 128 + col]);
    }
    // w2 [32][128] -> slots (kt*2+nt), kt<4, nt<2
    for (int i = t; i < 4096; i += nthr) {
        int e = i & 7, lane = (i >> 3) & 63, slot = i >> 9;
        int nt = slot & 1, kt = slot >> 1;
        int row = nt * 16 + (lane & 15), col = kt * 32 + (lane >> 4) * 8 + e;
        w2b[i] = f2bf(w2[row * 128 + col]);
    }
}

// ---------------- transpose x -> bf16 xT[bn][y][x][c]; fused agent-0 var sums ----------------
__global__ __launch_bounds__(256) void k_transpose(const float* __restrict__ x, unsigned short* __restrict__ xT,
                                                   float* __restrict__ vsum) {
    int bn = blockIdx.x / 96, y = blockIdx.x % 96;
    __shared__ float tile[96][129];
    const float* src = x + (size_t)bn * 128 * HW + (size_t)y * 96;
    for (int i = threadIdx.x; i < 128 * 96; i += 256) {
        int c = i / 96, xx = i - c * 96;
        tile[xx][c] = src[(size_t)c * HW + xx];
    }
    __syncthreads();
    unsigned int* dst = (unsigned int*)(xT + ((size_t)bn * 96 + y) * 96 * 128);
    for (int i = threadIdx.x; i < 96 * 64; i += 256) {
        int xx = i >> 6, cp = i & 63;
        unsigned int pk = (unsigned int)f2bf(tile[xx][cp * 2]) | ((unsigned int)f2bf(tile[xx][cp * 2 + 1]) << 16);
        dst[xx * 64 + cp] = pk;
    }
    if ((bn & 3) == 0 && threadIdx.x < 128) {
        int c = threadIdx.x;
        float s = 0.f, ss = 0.f;
        #pragma unroll 8
        for (int xx = 0; xx < 96; xx++) { float v = tile[xx][c]; s += v; ss += v * v; }
        float* vp = vsum + (size_t)((bn >> 2) * 128 + c) * 2;
        atomicAdd(vp, s);
        atomicAdd(vp + 1, ss);
    }
}

// ---------------- argmax of per-channel variance (ddof=1) ----------------
__global__ void k_argmax(const float* __restrict__ vsum, int* __restrict__ cmax) {
    int b = blockIdx.x, t = threadIdx.x;  // 128 threads
    __shared__ float v[128]; __shared__ int idx[128];
    float s = vsum[(b * 128 + t) * 2], ss = vsum[(b * 128 + t) * 2 + 1];
    float mean = s / 9216.f;
    v[t] = (ss - 9216.f * mean * mean) / 9215.f;
    idx[t] = t; __syncthreads();
    for (int o = 64; o > 0; o >>= 1) {
        if (t < o) { if (v[t + o] > v[t]) { v[t] = v[t + o]; idx[t] = idx[t + o]; } }
        __syncthreads();
    }
    if (t == 0) cmax[b] = idx[0];
}

// ---------------- mega-fused: inline gather -> 4-source MLP -> softmax -> combine -> final GEMM ----
// 256 thr (4 waves), 16 px/block, 1152 blocks. Wave w handles source j=w end-to-end.
// Staging now does the bilinear warp (j=1..3) inline from xT — SEL16/ROI buffers eliminated.
__global__ __launch_bounds__(256, 4) void k_fused(
    const unsigned short* __restrict__ xT, const float* __restrict__ th, const int* __restrict__ cmax,
    const unsigned short* __restrict__ w1b, const unsigned short* __restrict__ w2b,
    const unsigned short* __restrict__ mwb,
    const float* __restrict__ b1, const float* __restrict__ s1, const float* __restrict__ t1,
    const float* __restrict__ b2, const float* __restrict__ s2, const float* __restrict__ t2,
    const float* __restrict__ w3, const float* __restrict__ b3, const float* __restrict__ s3,
    const float* __restrict__ t3, const float* __restrict__ w4, const float* __restrict__ b4,
    const float* __restrict__ mb, float* __restrict__ out) {
    __shared__ __align__(16) unsigned char sm[34560];
    float* lgs  = (float*)(sm + 32768);
    float* rois = (float*)(sm + 33024);
    float* w3s  = (float*)(sm + 33280);
    float* cs3  = (float*)(sm + 34432);
    int t = threadIdx.x;
    int blk = blockIdx.x;
    int b = blk / 576, pt = blk - b * 576;
    int p0 = pt * 16;
    // ---- stage: ego (slot 0) + inline-gathered sel j=1..3, swizzled ----
    const unsigned short* egb = xT + (size_t)(b * 4) * HW * CC;
    {
        int px = t >> 4, g = t & 15;
        int p = p0 + px;
        int h = p / 96, w = p - h * 96;
        s16x8 ve = *(const s16x8*)(egb + (size_t)((95 - w) * 96 + h) * CC + g * 8);
        *(s16x8*)(sm + px * 256 + ((g * 16) ^ ((px & 7) << 4))) = ve;
        if (g == 0) rois[px] = 1.f;
        int cm = cmax[b];
        float X = -1.f + (2.f / 95.f) * (float)w, Y = -1.f + (2.f / 95.f) * (float)h;
        #pragma unroll
        for (int j = 1; j < 4; j++) {
            const float* t6 = th + (b * 4 + j) * 6;
            float gx = t6[0] * X + t6[1] * Y + t6[2];
            float gy = t6[3] * X + t6[4] * Y + t6[5];
            float pxf = (gx + 1.f) * 47.5f, pyf = (gy + 1.f) * 47.5f;
            float x0f = floorf(pxf), y0f = floorf(pyf);
            float wx = pxf - x0f, wy = pyf - y0f;
            int x0 = (int)x0f, y0 = (int)y0f, x1 = x0 + 1, y1 = y0 + 1;
            float w00 = (1.f - wx) * (1.f - wy), w10 = wx * (1.f - wy);
            float w01 = (1.f - wx) * wy, w11 = wx * wy;
            bool vx0 = (x0 >= 0) && (x0 <= 95), vx1 = (x1 >= 0) && (x1 <= 95);
            bool vy0 = (y0 >= 0) && (y0 <= 95), vy1 = (y1 >= 0) && (y1 <= 95);
            float f00 = (vx0 && vy0) ? w00 : 0.f, f10 = (vx1 && vy0) ? w10 : 0.f;
            float f01 = (vx0 && vy1) ? w01 : 0.f, f11 = (vx1 && vy1) ? w11 : 0.f;
            int xc0 = min(max(x0, 0), 95), xc1 = min(max(x1, 0), 95);
            int yc0 = min(max(y0, 0), 95), yc1 = min(max(y1, 0), 95);
            const unsigned short* base = xT + (size_t)(b * 4 + j) * HW * CC;
            s16x8 v00 = *(const s16x8*)(base + (size_t)((95 - xc0) * 96 + yc0) * CC + g * 8);
            s16x8 v10 = *(const s16x8*)(base + (size_t)((95 - xc1) * 96 + yc0) * CC + g * 8);
            s16x8 v01 = *(const s16x8*)(base + (size_t)((95 - xc0) * 96 + yc1) * CC + g * 8);
            s16x8 v11 = *(const s16x8*)(base + (size_t)((95 - xc1) * 96 + yc1) * CC + g * 8);
            s16x8 sv;
            #pragma unroll
            for (int e = 0; e < 8; e++) {
                float nb = f00 * bf2f((unsigned short)v00[e]) + f10 * bf2f((unsigned short)v10[e])
                         + f01 * bf2f((unsigned short)v01[e]) + f11 * bf2f((unsigned short)v11[e]);
                int c = g * 8 + e;
                sv[e] = (b == 0 || c == cm) ? (short)f2bf(nb) : ve[e];
            }
            *(s16x8*)(sm + j * 4096 + px * 256 + ((g * 16) ^ ((px & 7) << 4))) = sv;
            if (g == 0) rois[j * 16 + px] = f00 + f10 + f01 + f11;
        }
    }
    { int o = t >> 5, k = t & 31; w3s[o * 36 + k] = w3[o * 32 + k]; }
    if (t < 8) { cs3[t] = b3[t]; cs3[8 + t] = s3[t]; cs3[16 + t] = t3[t]; cs3[24 + t] = w4[t]; }
    int lane = t & 63, w_ = t >> 6, l15 = lane & 15, l4 = lane >> 4;
    unsigned char* scratch = sm + 16384 + w_ * 4096;
    __syncthreads();   // barrier 1
    // ---- GEMM1 (source j=w_): C[16px][128] = [sel_j || ego][16][256] @ W1^T ----
    f32x4 acc[8];
    #pragma unroll
    for (int nt = 0; nt < 8; nt++) acc[nt] = f32x4{0.f, 0.f, 0.f, 0.f};
    const unsigned char* tj = sm + w_ * 4096;
    #pragma unroll
    for (int kt = 0; kt < 8; kt++) {
        const unsigned char* asrc = (kt < 4) ? tj : sm;   // cols 128..255 = ego tile
        int kb = (kt & 3) * 64 + l4 * 16;
        s16x8 af = *(const s16x8*)(asrc + l15 * 256 + (kb ^ ((l15 & 7) << 4)));
        #pragma unroll
        for (int nt = 0; nt < 8; nt++) {
            s16x8 bf = *(const s16x8*)(w1b + (size_t)((kt * 8 + nt) * 64 + lane) * 8);
            acc[nt] = __builtin_amdgcn_mfma_f32_16x16x32_bf16(af, bf, acc[nt], 0, 0, 0);
        }
    }
    // ---- epilogue1: affine+relu -> wave-private l1T bf16 [16][128] swizzled ----
    #pragma unroll
    for (int nt = 0; nt < 8; nt++) {
        int o = nt * 16 + l15;
        float bb = b1[o], sv = s1[o], tv = t1[o];
        #pragma unroll
        for (int r = 0; r < 4; r++) {
            int px = l4 * 4 + r;
            float v = fmaxf((acc[nt][r] + bb) * sv + tv, 0.f);
            *(unsigned short*)(scratch + px * 256 + ((2 * o) ^ ((px & 7) << 4))) = f2bf(v);
        }
    }
    asm volatile("s_waitcnt lgkmcnt(0)" ::: "memory");
    // ---- GEMM2: C[16px][32] = L1[16][128] @ W2^T (whole wave) ----
    f32x4 acc2[2];
    acc2[0] = f32x4{0.f, 0.f, 0.f, 0.f};
    acc2[1] = f32x4{0.f, 0.f, 0.f, 0.f};
    #pragma unroll
    for (int kt = 0; kt < 4; kt++) {
        s16x8 af2 = *(const s16x8*)(scratch + l15 * 256 + ((2 * (kt * 32 + l4 * 8)) ^ ((l15 & 7) << 4)));
        #pragma unroll
        for (int nt = 0; nt < 2; nt++) {
            s16x8 bf = *(const s16x8*)(w2b + (size_t)((kt * 2 + nt) * 64 + lane) * 8);
            acc2[nt] = __builtin_amdgcn_mfma_f32_16x16x32_bf16(af2, bf, acc2[nt], 0, 0, 0);
        }
    }
    asm volatile("s_waitcnt lgkmcnt(0)" ::: "memory");
    // ---- epilogue2: affine+relu -> l2s f32 [16][36] (overlays scratch; same wave only) ----
    float* l2s = (float*)scratch;
    #pragma unroll
    for (int nt = 0; nt < 2; nt++) {
        int o = nt * 16 + l15;
        float bb = b2[o], sv = s2[o], tv = t2[o];
        #pragma unroll
        for (int r = 0; r < 4; r++) {
            int px = l4 * 4 + r;
            l2s[px * 36 + o] = fmaxf((acc2[nt][r] + bb) * sv + tv, 0.f);
        }
    }
    asm volatile("s_waitcnt lgkmcnt(0)" ::: "memory");
    // ---- layers 3+4 fp32 (lanes 0..15 of EVERY wave, concurrent across sources) ----
    if (lane < 16) {
        int px = lane;
        f32x4 xv[8];
        #pragma unroll
        for (int kc = 0; kc < 8; kc++) xv[kc] = *(const f32x4*)(l2s + px * 36 + kc * 4);
        float lg = b4[0];
        #pragma unroll
        for (int o = 0; o < 8; o++) {
            float a = 0.f;
            #pragma unroll
            for (int kc = 0; kc < 8; kc++) {
                f32x4 wv = *(const f32x4*)(w3s + o * 36 + kc * 4);
                a += xv[kc][0] * wv[0] + xv[kc][1] * wv[1] + xv[kc][2] * wv[2] + xv[kc][3] * wv[3];
            }
            float l3 = fmaxf((a + cs3[o]) * cs3[8 + o] + cs3[16 + o], 0.f);
            lg += cs3[24 + o] * l3;
        }
        lgs[w_ * 16 + px] = fmaxf(lg, 0.f);
    }
    __syncthreads();   // barrier 2
    // ---- softmax weights (per lane, for its A-frag row px = l15) ----
    float wgt[4];
    {
        int px = l15;
        float rr[4], lg[4];
        #pragma unroll
        for (int j = 0; j < 4; j++) { rr[j] = rois[j * 16 + px]; lg[j] = lgs[j * 16 + px]; }
        float m = -1e30f;
        #pragma unroll
        for (int j = 0; j < 4; j++) if (rr[j] != 0.f && lg[j] > m) m = lg[j];
        float e[4], se = 0.f;
        #pragma unroll
        for (int j = 0; j < 4; j++) { e[j] = (rr[j] != 0.f) ? expf(lg[j] - m) : 0.f; se += e[j]; }
        float inv = 1.f / se;
        #pragma unroll
        for (int j = 0; j < 4; j++) wgt[j] = e[j] * inv * rr[j];
    }
    // ---- combine (in-register, from LDS tiles) + final GEMM; wave owns out cols w_*32..+31 ----
    f32x4 acc3[2];
    acc3[0] = f32x4{0.f, 0.f, 0.f, 0.f};
    acc3[1] = f32x4{0.f, 0.f, 0.f, 0.f};
    #pragma unroll
    for (int kt = 0; kt < 4; kt++) {
        int byo = (kt * 64 + l4 * 16) ^ ((l15 & 7) << 4);
        float accv[8];
        #pragma unroll
        for (int e = 0; e < 8; e++) accv[e] = 0.f;
        #pragma unroll
        for (int j = 0; j < 4; j++) {
            s16x8 v = *(const s16x8*)(sm + j * 4096 + l15 * 256 + byo);
            float wj = wgt[j];
            #pragma unroll
            for (int e = 0; e < 8; e++) accv[e] += wj * bf2f((unsigned short)v[e]);
        }
        s16x8 af;
        #pragma unroll
        for (int e = 0; e < 8; e++) af[e] = (short)f2bf(accv[e]);
        #pragma unroll
        for (int nt = 0; nt < 2; nt++) {
            s16x8 bfr = *(const s16x8*)(mwb + (size_t)((w_ * 8 + kt * 2 + nt) * 64 + lane) * 8);
            acc3[nt] = __builtin_amdgcn_mfma_f32_16x16x32_bf16(af, bfr, acc3[nt], 0, 0, 0);
        }
    }
    float mbv[2];
    #pragma unroll
    for (int nt = 0; nt < 2; nt++) mbv[nt] = mb[w_ * 32 + nt * 16 + l15];
    #pragma unroll
    for (int nt = 0; nt < 2; nt++) {
        #pragma unroll
        for (int r = 0; r < 4; r++) {
            int px = l4 * 4 + r;
            int p = p0 + px;
            int h = p / 96, ww = p - h * 96;
            out[(((size_t)b * 96 + (95 - ww)) * 96 + h) * CC + w_ * 32 + nt * 16 + l15] = acc3[nt][r] + mbv[nt];
        }
    }
}

extern "C" void kernel_launch(void* const* d_in, const int* in_sizes, int n_in,
                              void* d_out, int out_size, void* d_ws, size_t ws_size,
                              hipStream_t stream) {
    const float* x  = (const float*)d_in[0];
    const float* P  = (const float*)d_in[2];
    const float* w1 = (const float*)d_in[3];
    const float* b1 = (const float*)d_in[4];
    const float* s1 = (const float*)d_in[5];
    const float* t1 = (const float*)d_in[6];
    const float* w2 = (const float*)d_in[7];
    const float* b2 = (const float*)d_in[8];
    const float* s2 = (const float*)d_in[9];
    const float* t2 = (const float*)d_in[10];
    const float* w3 = (const float*)d_in[11];
    const float* b3 = (const float*)d_in[12];
    const float* s3 = (const float*)d_in[13];
    const float* t3 = (const float*)d_in[14];
    const float* w4 = (const float*)d_in[15];
    const float* b4 = (const float*)d_in[16];
    const float* mw = (const float*)d_in[17];
    const float* mb = (const float*)d_in[18];
    float* out = (float*)d_out;

    float* ws = (float*)d_ws;
    float* TH   = ws;                                     // 48 (pad 64)
    float* VSUM = ws + 64;                                // [2][128][2] = 512
    int*   CMX  = (int*)(ws + 576);                       // 2 (pad to 1024)
    unsigned short* XT  = (unsigned short*)(ws + 1024);   // 8*HW*128 = 9437184 bf16
    unsigned short* W1B = XT + 9437184;                   // 32768
    unsigned short* W2B = W1B + 32768;                    // 4096
    unsigned short* MWB = W2B + 4096;                     // 16384

    hipMemsetAsync(VSUM, 0, 512 * sizeof(float), stream);
    k_prep<<<16, 256, 0, stream>>>(P, w1, w2, mw, TH, W1B, W2B, MWB);
    k_transpose<<<768, 256, 0, stream>>>(x, XT, VSUM);
    k_argmax<<<2, 128, 0, stream>>>(VSUM, CMX);
    k_fused<<<1152, 256, 0, stream>>>(XT, TH, CMX, W1B, W2B, MWB,
                                      b1, s1, t1, b2, s2, t2, w3, b3, s3, t3, w4, b4, mb, out);
}